// Round 1
// baseline (1230.813 us; speedup 1.0000x reference)
//
#include <hip/hip_runtime.h>
#include <stdint.h>
#include <math.h>

#define NB 8
#define NQ 512

// ws layout (bytes):
//   [0      ) curr_xyxy : NB*NQ*4 f32  = 65536
//   [65536  ) filt_xyxy : NB*NQ*4 f32  = 65536
//   [131072 ) cost bits : NB*NQ*8 u64  = 262144   (bit j of word k of row i = cost[i][64k+j])
//   [393216 ) cols      : NB*NQ  i32   = 16384
//   [409600 ) sum       : 1 f32
// total 409604 bytes

__global__ void prep_kernel(const float* __restrict__ prev_boxes,
                            const float* __restrict__ curr_boxes,
                            const float* __restrict__ image_sizes,
                            float* __restrict__ curr_xyxy,
                            float* __restrict__ filt_xyxy,
                            float* __restrict__ sum) {
#pragma clang fp contract(off)
    int idx = blockIdx.x * blockDim.x + threadIdx.x;
    if (idx == 0) *sum = 0.f;
    if (idx >= NB * NQ) return;
    int b = idx >> 9;
    float H = image_sizes[2 * b + 0];
    float W = image_sizes[2 * b + 1];
    const float* pb = prev_boxes + 4 * idx;
    // filtered = (prev * scale) / scale, scale = [W,H,W,H]
    float fcx = (pb[0] * W) / W;
    float fcy = (pb[1] * H) / H;
    float fw  = (pb[2] * W) / W;
    float fh  = (pb[3] * H) / H;
    float4 f;
    f.x = fcx - 0.5f * fw; f.y = fcy - 0.5f * fh;
    f.z = fcx + 0.5f * fw; f.w = fcy + 0.5f * fh;
    ((float4*)filt_xyxy)[idx] = f;
    const float* cb = curr_boxes + 4 * idx;
    float ccx = cb[0], ccy = cb[1], cw = cb[2], ch = cb[3];
    float4 c;
    c.x = ccx - 0.5f * cw; c.y = ccy - 0.5f * ch;
    c.z = ccx + 0.5f * cw; c.w = ccy + 0.5f * ch;
    ((float4*)curr_xyxy)[idx] = c;
}

__global__ void cost_kernel(const float* __restrict__ curr_xyxy,
                            const float* __restrict__ filt_xyxy,
                            unsigned long long* __restrict__ cost) {
#pragma clang fp contract(off)
    int t = blockIdx.x * blockDim.x + threadIdx.x;   // 0 .. NB*NQ*NQ-1
    int b = t >> 18;
    int rem = t & (NQ * NQ - 1);
    int i = rem >> 9;
    int j = rem & (NQ - 1);
    float4 a  = ((const float4*)curr_xyxy)[(b << 9) + i];
    float4 bb = ((const float4*)filt_xyxy)[(b << 9) + j];
    float area_a = (a.z - a.x) * (a.w - a.y);
    float area_b = (bb.z - bb.x) * (bb.w - bb.y);
    float ltx = fmaxf(a.x, bb.x), lty = fmaxf(a.y, bb.y);
    float rbx = fminf(a.z, bb.z), rby = fminf(a.w, bb.w);
    float w = fmaxf(rbx - ltx, 0.f), h = fmaxf(rby - lty, 0.f);
    float inter = w * h;
    float uni = area_a + area_b - inter;
    float iou = inter / (uni + 1e-7f);
    float lcx = fminf(a.x, bb.x), lcy = fminf(a.y, bb.y);
    float rcx = fmaxf(a.z, bb.z), rcy = fmaxf(a.w, bb.w);
    float wc = fmaxf(rcx - lcx, 0.f), hc = fmaxf(rcy - lcy, 0.f);
    float areac = wc * hc;
    float giou = iou - (areac - uni) / (areac + 1e-7f);
    float gl = 1.f - giou;
    unsigned long long m = __ballot(gl < 0.2f);
    if ((threadIdx.x & 63) == 0)
        cost[((size_t)((b << 9) + i)) * 8 + (j >> 6)] = m;
}

// Exact integer replication of the reference JV Hungarian (float64 values are
// all exact small integers for a {0,1} cost matrix). One 64-lane wave per
// batch; lane L owns columns j where (j-1)&63 == L (8 cols/lane, state in
// registers). Shortcut: when no unused column has minv>0, all remaining
// visits are provable no-ops (cur >= 0 = minv by dual feasibility) -> jump
// to the lowest-index unused free column.
__global__ __launch_bounds__(64) void hungarian_kernel(
        const unsigned long long* __restrict__ cost, int* __restrict__ cols) {
    int b = blockIdx.x;
    int lane = threadIdx.x;
    __shared__ int p[NQ + 1];
    __shared__ int way[NQ + 1];
    __shared__ int u[NQ + 1];
    for (int k = lane; k <= NQ; k += 64) { p[k] = 0; u[k] = 0; way[k] = 0; }
    int v8[8], minv8[8];
#pragma unroll
    for (int k = 0; k < 8; k++) v8[k] = 0;
    __syncthreads();
    const unsigned long long* costb = cost + (size_t)b * NQ * 8;

    for (int i = 1; i <= NQ; i++) {
        if (lane == 0) p[0] = i;
        unsigned usedmask = 0;
#pragma unroll
        for (int k = 0; k < 8; k++) minv8[k] = 0x3fffffff;  // "inf"
        __syncthreads();
        int j0 = 0;
        while (true) {
            // used[j0] = true
            if (j0 > 0) {
                int jj = j0 - 1;
                if ((jj & 63) == lane) usedmask |= 1u << (jj >> 6);
            }
            int i0 = p[j0];
            int ui0 = u[i0];
            const unsigned long long* row = costb + (size_t)(i0 - 1) * 8;
            unsigned long long lk = ~0ull;
            bool anyPos = false;
#pragma unroll
            for (int k = 0; k < 8; k++) {
                if (!((usedmask >> k) & 1u)) {
                    int c = (int)((row[k] >> lane) & 1ull);
                    int cur = c - ui0 - v8[k];
                    int j = 1 + lane + (k << 6);
                    if (cur < minv8[k]) { minv8[k] = cur; way[j] = j0; }
                    int mv = minv8[k];
                    unsigned long long key =
                        ((unsigned long long)(unsigned)mv << 16) | (unsigned)j;
                    if (key < lk) lk = key;
                    anyPos |= (mv > 0);
                }
            }
            // wave min-reduce: smallest (minv, j) lexicographically
#pragma unroll
            for (int off = 32; off >= 1; off >>= 1) {
                unsigned long long o = __shfl_xor(lk, off, 64);
                if (o < lk) lk = o;
            }
            int j1 = (int)(lk & 0xffffull);
            int delta = (int)(lk >> 16);
            unsigned long long pos = __ballot(anyPos);
            if (delta != 0) {
#pragma unroll
                for (int k = 0; k < 8; k++) {
                    int j = 1 + lane + (k << 6);
                    if ((usedmask >> k) & 1u) { u[p[j]] += delta; v8[k] -= delta; }
                    else                       { minv8[k] -= delta; }
                }
                if (lane == 0) u[p[0]] += delta;  // virtual column 0 is used
                __syncthreads();
            }
            j0 = j1;
            if (p[j0] == 0) break;
            if (pos == 0ull) {
                // all unused minv == 0: remaining walk is a no-op; terminate at
                // the lowest-index unused free column
                unsigned lmin = 0xffffffffu;
#pragma unroll
                for (int k = 0; k < 8; k++) {
                    if (!((usedmask >> k) & 1u)) {
                        int j = 1 + lane + (k << 6);
                        if (p[j] == 0 && (unsigned)j < lmin) lmin = (unsigned)j;
                    }
                }
#pragma unroll
                for (int off = 32; off >= 1; off >>= 1) {
                    unsigned o = __shfl_xor(lmin, off, 64);
                    if (o < lmin) lmin = o;
                }
                j0 = (int)lmin;
                break;
            }
        }
        __syncthreads();
        if (lane == 0) {
            int jc = j0;
            while (jc) { int jn = way[jc]; p[jc] = p[jn]; jc = jn; }
        }
        __syncthreads();
    }
#pragma unroll
    for (int k = 0; k < 8; k++) {
        int j = 1 + lane + (k << 6);
        cols[b * NQ + (p[j] - 1)] = j - 1;
    }
}

__global__ void ciou_kernel(const float* __restrict__ curr_xyxy,
                            const float* __restrict__ filt_xyxy,
                            const int* __restrict__ cols,
                            float* __restrict__ sum) {
#pragma clang fp contract(off)
    int idx = blockIdx.x * blockDim.x + threadIdx.x;
    float term = 0.f;
    if (idx < NB * NQ) {
        int b = idx >> 9;
        int c = cols[idx];
        float4 pv = ((const float4*)curr_xyxy)[(b << 9) + c];
        float4 tv = ((const float4*)filt_xyxy)[idx];
        float x1 = pv.x, y1 = pv.y, x2 = pv.z, y2 = pv.w;
        float xg1 = tv.x, yg1 = tv.y, xg2 = tv.z, yg2 = tv.w;
        float iw = fmaxf(fminf(x2, xg2) - fmaxf(x1, xg1), 0.f);
        float ih = fmaxf(fminf(y2, yg2) - fmaxf(y1, yg1), 0.f);
        float inter = iw * ih;
        float uni = (x2 - x1) * (y2 - y1) + (xg2 - xg1) * (yg2 - yg1) - inter;
        float iou = inter / (uni + 1e-7f);
        float cw = fmaxf(x2, xg2) - fminf(x1, xg1);
        float ch = fmaxf(y2, yg2) - fminf(y1, yg1);
        float c2 = cw * cw + ch * ch + 1e-7f;
        float dx = ((x1 + x2) - xg1) - xg2;
        float dy = ((y1 + y2) - yg1) - yg2;
        float d2 = (dx * dx + dy * dy) / 4.f;
        const float C = (float)(4.0 / (M_PI * M_PI));
        float at = atanf((xg2 - xg1) / (yg2 - yg1)) - atanf((x2 - x1) / (y2 - y1));
        float v = C * (at * at);
        float alpha = v / (((1.f - iou) + v) + 1e-7f);
        term = ((1.f - iou) + d2 / c2) + alpha * v;
    }
#pragma unroll
    for (int off = 32; off >= 1; off >>= 1) term += __shfl_xor(term, off, 64);
    if ((threadIdx.x & 63) == 0) atomicAdd(sum, term);
}

__global__ void finalize_kernel(const float* __restrict__ sum,
                                float* __restrict__ out) {
    if (threadIdx.x == 0 && blockIdx.x == 0) out[0] = sum[0] * (1.f / 4096.f);
}

extern "C" void kernel_launch(void* const* d_in, const int* in_sizes, int n_in,
                              void* d_out, int out_size, void* d_ws, size_t ws_size,
                              hipStream_t stream) {
    const float* prev_boxes  = (const float*)d_in[0];
    // d_in[1] = prev_logits : dead code (innovation == 0 exactly)
    const float* curr_boxes  = (const float*)d_in[2];
    const float* image_sizes = (const float*)d_in[3];
    // d_in[4..6] (std weights, log_q_diag) : dead code

    char* ws = (char*)d_ws;
    float* curr_xyxy = (float*)(ws);
    float* filt_xyxy = (float*)(ws + 65536);
    unsigned long long* cost = (unsigned long long*)(ws + 131072);
    int* cols  = (int*)(ws + 393216);
    float* sum = (float*)(ws + 409600);
    float* out = (float*)d_out;

    prep_kernel<<<16, 256, 0, stream>>>(prev_boxes, curr_boxes, image_sizes,
                                        curr_xyxy, filt_xyxy, sum);
    cost_kernel<<<(NB * NQ * NQ) / 256, 256, 0, stream>>>(curr_xyxy, filt_xyxy, cost);
    hungarian_kernel<<<NB, 64, 0, stream>>>(cost, cols);
    ciou_kernel<<<16, 256, 0, stream>>>(curr_xyxy, filt_xyxy, cols, sum);
    finalize_kernel<<<1, 64, 0, stream>>>(sum, out);
}

// Round 2
// 270.854 us; speedup vs baseline: 4.5442x; 4.5442x over previous
//
#include <hip/hip_runtime.h>
#include <stdint.h>
#include <math.h>

#define NB 8
#define NQ 512

// ws layout (bytes):
//   [0      ) curr_xyxy : NB*NQ*4 f32  = 65536
//   [65536  ) filt_xyxy : NB*NQ*4 f32  = 65536
//   [131072 ) cost bits : NB*NQ*8 u64  = 262144   (bit j of word k of row i = cost[i][64k+j])
//   [393216 ) cols      : NB*NQ  i32   = 16384
// total 409600 bytes

__global__ void prep_kernel(const float* __restrict__ prev_boxes,
                            const float* __restrict__ curr_boxes,
                            const float* __restrict__ image_sizes,
                            float* __restrict__ curr_xyxy,
                            float* __restrict__ filt_xyxy,
                            float* __restrict__ out) {
#pragma clang fp contract(off)
    int idx = blockIdx.x * blockDim.x + threadIdx.x;
    if (idx == 0) out[0] = 0.f;
    if (idx >= NB * NQ) return;
    int b = idx >> 9;
    float H = image_sizes[2 * b + 0];
    float W = image_sizes[2 * b + 1];
    const float* pb = prev_boxes + 4 * idx;
    // filtered = (prev * scale) / scale, scale = [W,H,W,H]  (Kalman innovation == 0 exactly)
    float fcx = (pb[0] * W) / W;
    float fcy = (pb[1] * H) / H;
    float fw  = (pb[2] * W) / W;
    float fh  = (pb[3] * H) / H;
    float4 f;
    f.x = fcx - 0.5f * fw; f.y = fcy - 0.5f * fh;
    f.z = fcx + 0.5f * fw; f.w = fcy + 0.5f * fh;
    ((float4*)filt_xyxy)[idx] = f;
    const float* cb = curr_boxes + 4 * idx;
    float ccx = cb[0], ccy = cb[1], cw = cb[2], ch = cb[3];
    float4 c;
    c.x = ccx - 0.5f * cw; c.y = ccy - 0.5f * ch;
    c.z = ccx + 0.5f * cw; c.w = ccy + 0.5f * ch;
    ((float4*)curr_xyxy)[idx] = c;
}

__global__ void cost_kernel(const float* __restrict__ curr_xyxy,
                            const float* __restrict__ filt_xyxy,
                            unsigned long long* __restrict__ cost) {
#pragma clang fp contract(off)
    int t = blockIdx.x * blockDim.x + threadIdx.x;   // 0 .. NB*NQ*NQ-1
    int b = t >> 18;
    int rem = t & (NQ * NQ - 1);
    int i = rem >> 9;
    int j = rem & (NQ - 1);
    float4 a  = ((const float4*)curr_xyxy)[(b << 9) + i];
    float4 bb = ((const float4*)filt_xyxy)[(b << 9) + j];
    float area_a = (a.z - a.x) * (a.w - a.y);
    float area_b = (bb.z - bb.x) * (bb.w - bb.y);
    float ltx = fmaxf(a.x, bb.x), lty = fmaxf(a.y, bb.y);
    float rbx = fminf(a.z, bb.z), rby = fminf(a.w, bb.w);
    float w = fmaxf(rbx - ltx, 0.f), h = fmaxf(rby - lty, 0.f);
    float inter = w * h;
    float uni = area_a + area_b - inter;
    float iou = inter / (uni + 1e-7f);
    float lcx = fminf(a.x, bb.x), lcy = fminf(a.y, bb.y);
    float rcx = fmaxf(a.z, bb.z), rcy = fmaxf(a.w, bb.w);
    float wc = fmaxf(rcx - lcx, 0.f), hc = fmaxf(rcy - lcy, 0.f);
    float areac = wc * hc;
    float giou = iou - (areac - uni) / (areac + 1e-7f);
    float gl = 1.f - giou;
    unsigned long long m = __ballot(gl < 0.2f);
    if ((threadIdx.x & 63) == 0)
        cost[((size_t)((b << 9) + i)) * 8 + (j >> 6)] = m;
}

// Exact integer replication of the reference JV Hungarian on a {0,1} cost
// matrix, run by ONE thread per batch with 512-bit bitset state in scalar
// registers. Fast path (valid while all duals are zero — i.e. until a
// delta>0 event, which for sparse 1s essentially never occurs):
//   - all-zero cost row: search collapses to "assign lowest free column"
//     (iter1 sets minv=0,way=0 everywhere; shortcut fires) — no memory.
//   - nonzero row: minv ∈ {0,1}; minv==1 set == AND of visited rows' 1-bits
//     (ones_acc). j1 = ctz(~ones_acc & ~visited); way updates only at
//     newly-zeroed bits. Shortcut: if (ones_acc & ~visited)==0 the rest of
//     the walk is a provable no-op -> terminate at lowest free column.
//   - if all unvisited minv>0 (delta>0 needed): bail, re-run this row and
//     all subsequent rows in the fully general integer JV (exact reference
//     semantics incl. first-minimum tie-break).
// way[] uses version-tag packing: way[j] = (i<<10)|j0, read as 0 unless the
// tag matches the current row — no per-row memset.
__global__ __launch_bounds__(64) void hungarian_kernel(
        const unsigned long long* __restrict__ cost, int* __restrict__ cols) {
    int b = blockIdx.x;
    int lane = threadIdx.x;
    __shared__ int p[NQ + 1];
    __shared__ int way[NQ + 1];
    __shared__ int u[NQ + 1];
    __shared__ int vv[NQ + 1];
    __shared__ int minv[NQ + 1];
    __shared__ unsigned char used[NQ + 1];
    __shared__ unsigned long long rows_nz_sh[8];
    for (int k = lane; k <= NQ; k += 64) { p[k] = 0; way[k] = 0; u[k] = 0; vv[k] = 0; }
    const unsigned long long* costb = cost + (size_t)b * NQ * 8;
    // wave-parallel: which rows have any 1-bit
    for (int w = 0; w < 8; w++) {
        int r = (w << 6) + lane;
        const unsigned long long* rw = costb + (size_t)r * 8;
        unsigned long long o = 0ull;
#pragma unroll
        for (int k = 0; k < 8; k++) o |= rw[k];
        unsigned long long bal = __ballot(o != 0ull);
        if (lane == 0) rows_nz_sh[w] = bal;
    }
    __syncthreads();
    if (lane == 0) {
        unsigned long long freeb[8];
#pragma unroll
        for (int k = 0; k < 8; k++) freeb[k] = ~0ull;
        bool general = false;
        for (int w = 0; w < 8; w++) {
            unsigned long long nzw = rows_nz_sh[w];
            for (int bb = 0; bb < 64; bb++) {
                int i = (w << 6) + bb + 1;
                bool handled = false;
                if (!general) {
                    if (!((nzw >> bb) & 1ull)) {
                        // zero row: take lowest free column, way stays 0
                        int jf = 0;
#pragma unroll
                        for (int k = 0; k < 8; k++) {
                            if (jf == 0 && freeb[k]) {
                                jf = (k << 6) + __builtin_ctzll(freeb[k]) + 1;
                                freeb[k] &= freeb[k] - 1;
                            }
                        }
                        p[jf] = i;
                        handled = true;
                    } else {
                        // bitset search, duals all zero
                        unsigned long long visited[8], ones[8];
                        const unsigned long long* ri = costb + (size_t)(i - 1) * 8;
#pragma unroll
                        for (int k = 0; k < 8; k++) { visited[k] = 0ull; ones[k] = ri[k]; }
                        while (true) {
                            int j1 = 0;
#pragma unroll
                            for (int k = 0; k < 8; k++) {
                                unsigned long long s0 = ~ones[k] & ~visited[k];
                                if (j1 == 0 && s0) j1 = (k << 6) + __builtin_ctzll(s0) + 1;
                            }
                            if (j1 == 0) { general = true; break; }  // delta>0 needed
                            if (p[j1] == 0) {
                                int j = j1;
                                while (j) {
                                    int wvv = way[j];
                                    int jn = ((wvv >> 10) == i) ? (wvv & 1023) : 0;
                                    p[j] = jn ? p[jn] : i;
                                    j = jn;
                                }
                                int wd = (j1 - 1) >> 6;
                                unsigned long long m = ~(1ull << ((j1 - 1) & 63));
#pragma unroll
                                for (int k = 0; k < 8; k++) if (k == wd) freeb[k] &= m;
                                handled = true;
                                break;
                            }
                            // anyPos: any unvisited col with minv==1?
                            unsigned long long ap = 0ull;
#pragma unroll
                            for (int k = 0; k < 8; k++) ap |= ones[k] & ~visited[k];
                            if (ap == 0ull) {
                                // shortcut: rest of walk is a no-op; lowest free col
                                int jf = 0;
#pragma unroll
                                for (int k = 0; k < 8; k++)
                                    if (jf == 0 && freeb[k])
                                        jf = (k << 6) + __builtin_ctzll(freeb[k]) + 1;
                                int j = jf;
                                while (j) {
                                    int wvv = way[j];
                                    int jn = ((wvv >> 10) == i) ? (wvv & 1023) : 0;
                                    p[j] = jn ? p[jn] : i;
                                    j = jn;
                                }
                                int wd = (jf - 1) >> 6;
                                unsigned long long m = ~(1ull << ((jf - 1) & 63));
#pragma unroll
                                for (int k = 0; k < 8; k++) if (k == wd) freeb[k] &= m;
                                handled = true;
                                break;
                            }
                            // visit j1: fold owner's row into minv
                            {
                                int wd = (j1 - 1) >> 6;
                                unsigned long long m = 1ull << ((j1 - 1) & 63);
#pragma unroll
                                for (int k = 0; k < 8; k++) if (k == wd) visited[k] |= m;
                            }
                            int owner = p[j1];
                            const unsigned long long* rr = costb + (size_t)(owner - 1) * 8;
#pragma unroll
                            for (int k = 0; k < 8; k++) {
                                unsigned long long rwv = rr[k];
                                unsigned long long nzb = ones[k] & ~rwv & ~visited[k];
                                ones[k] &= rwv;
                                while (nzb) {
                                    int bbit = __builtin_ctzll(nzb);
                                    nzb &= nzb - 1;
                                    way[(k << 6) + bbit + 1] = (i << 10) | j1;
                                }
                            }
                        }
                    }
                }
                if (!handled) {
                    // fully general integer JV (exact reference semantics)
                    p[0] = i;
                    for (int j = 0; j <= NQ; j++) { minv[j] = 0x7fffffff; used[j] = 0; }
                    int j0 = 0;
                    while (true) {
                        used[j0] = 1;
                        int i0 = p[j0];
                        int ui0 = u[i0];
                        const unsigned long long* rr = costb + (size_t)(i0 - 1) * 8;
                        int delta = 0x7fffffff, j1 = 0;
                        for (int j = 1; j <= NQ; j++) {
                            if (!used[j]) {
                                int c = (int)((rr[(j - 1) >> 6] >> ((j - 1) & 63)) & 1ull);
                                int cur = c - ui0 - vv[j];
                                if (cur < minv[j]) { minv[j] = cur; way[j] = (i << 10) | j0; }
                                if (minv[j] < delta) { delta = minv[j]; j1 = j; }
                            }
                        }
                        for (int j = 0; j <= NQ; j++) {
                            if (used[j]) { u[p[j]] += delta; vv[j] -= delta; }
                            else minv[j] -= delta;
                        }
                        j0 = j1;
                        if (p[j0] == 0) break;
                    }
                    while (j0) {
                        int wvv = way[j0];
                        int jn = ((wvv >> 10) == i) ? (wvv & 1023) : 0;
                        p[j0] = p[jn];
                        j0 = jn;
                    }
                }
            }
        }
    }
    __syncthreads();
#pragma unroll
    for (int k = 0; k < 8; k++) {
        int j = 1 + lane + (k << 6);
        cols[b * NQ + (p[j] - 1)] = j - 1;
    }
}

__global__ void ciou_kernel(const float* __restrict__ curr_xyxy,
                            const float* __restrict__ filt_xyxy,
                            const int* __restrict__ cols,
                            float* __restrict__ out) {
#pragma clang fp contract(off)
    int idx = blockIdx.x * blockDim.x + threadIdx.x;
    float term = 0.f;
    if (idx < NB * NQ) {
        int b = idx >> 9;
        int c = cols[idx];
        float4 pv = ((const float4*)curr_xyxy)[(b << 9) + c];
        float4 tv = ((const float4*)filt_xyxy)[idx];
        float x1 = pv.x, y1 = pv.y, x2 = pv.z, y2 = pv.w;
        float xg1 = tv.x, yg1 = tv.y, xg2 = tv.z, yg2 = tv.w;
        float iw = fmaxf(fminf(x2, xg2) - fmaxf(x1, xg1), 0.f);
        float ih = fmaxf(fminf(y2, yg2) - fmaxf(y1, yg1), 0.f);
        float inter = iw * ih;
        float uni = (x2 - x1) * (y2 - y1) + (xg2 - xg1) * (yg2 - yg1) - inter;
        float iou = inter / (uni + 1e-7f);
        float cw = fmaxf(x2, xg2) - fminf(x1, xg1);
        float ch = fmaxf(y2, yg2) - fminf(y1, yg1);
        float c2 = cw * cw + ch * ch + 1e-7f;
        float dx = ((x1 + x2) - xg1) - xg2;
        float dy = ((y1 + y2) - yg1) - yg2;
        float d2 = (dx * dx + dy * dy) / 4.f;
        const float C = (float)(4.0 / (M_PI * M_PI));
        float at = atanf((xg2 - xg1) / (yg2 - yg1)) - atanf((x2 - x1) / (y2 - y1));
        float v = C * (at * at);
        float alpha = v / (((1.f - iou) + v) + 1e-7f);
        term = ((1.f - iou) + d2 / c2) + alpha * v;
    }
#pragma unroll
    for (int off = 32; off >= 1; off >>= 1) term += __shfl_xor(term, off, 64);
    if ((threadIdx.x & 63) == 0) atomicAdd(out, term * (1.f / 4096.f));
}

extern "C" void kernel_launch(void* const* d_in, const int* in_sizes, int n_in,
                              void* d_out, int out_size, void* d_ws, size_t ws_size,
                              hipStream_t stream) {
    const float* prev_boxes  = (const float*)d_in[0];
    // d_in[1] = prev_logits : dead code (Kalman innovation == 0 exactly)
    const float* curr_boxes  = (const float*)d_in[2];
    const float* image_sizes = (const float*)d_in[3];
    // d_in[4..6] (std weights, log_q_diag) : dead code

    char* ws = (char*)d_ws;
    float* curr_xyxy = (float*)(ws);
    float* filt_xyxy = (float*)(ws + 65536);
    unsigned long long* cost = (unsigned long long*)(ws + 131072);
    int* cols  = (int*)(ws + 393216);
    float* out = (float*)d_out;

    prep_kernel<<<16, 256, 0, stream>>>(prev_boxes, curr_boxes, image_sizes,
                                        curr_xyxy, filt_xyxy, out);
    cost_kernel<<<(NB * NQ * NQ) / 256, 256, 0, stream>>>(curr_xyxy, filt_xyxy, cost);
    hungarian_kernel<<<NB, 64, 0, stream>>>(cost, cols);
    ciou_kernel<<<16, 256, 0, stream>>>(curr_xyxy, filt_xyxy, cols, out);
}